// Round 2
// baseline (761.421 us; speedup 1.0000x reference)
//
#include <hip/hip_runtime.h>
#include <hip/hip_bf16.h>

#define Bb 2
#define Ss 2048
#define Dd 1024
#define Hh 16

typedef short bf16x8 __attribute__((ext_vector_type(8)));
typedef short bf16x4 __attribute__((ext_vector_type(4)));
typedef float floatx4 __attribute__((ext_vector_type(4)));
typedef unsigned short u16;

__device__ inline void gld16(void* lds, const void* g) {
  __builtin_amdgcn_global_load_lds(
      (const __attribute__((address_space(1))) unsigned int*)g,
      (__attribute__((address_space(3))) unsigned int*)lds, 16, 0, 0);
}

__device__ inline float bf2f(u16 u) {
  unsigned int x = ((unsigned int)u) << 16;
  float f; __builtin_memcpy(&f, &x, 4); return f;
}
__device__ inline u16 f2bf(float f) {
  unsigned int x; __builtin_memcpy(&x, &f, 4);
  x = (x + 0x7fff + ((x >> 16) & 1)) >> 16;   // RNE
  return (u16)x;
}

// ---------------- dtype sniffer: finite bf16 data never has exponent 0xFF;
// f32 data read as u16 pairs has ~1/256 exponent-0xFF in the mantissa half.
__global__ void sniff(const unsigned int* __restrict__ x, unsigned int* __restrict__ flag,
                      int nwords) {
  __shared__ int cnt;
  if (threadIdx.x == 0) cnt = 0;
  __syncthreads();
  int local = 0;
  for (int i = threadIdx.x; i < nwords; i += blockDim.x) {
    unsigned int wd = x[i];
    if (((wd >> 7)  & 0xFFu) == 0xFFu) local++;   // low-half bf16 exponent
    if (((wd >> 23) & 0xFFu) == 0xFFu) local++;   // high-half bf16 / f32 exponent
  }
  atomicAdd(&cnt, local);
  __syncthreads();
  if (threadIdx.x == 0) *flag = (cnt >= 64) ? 1u : 0u;
}

// ---------------- normalize any input tensor to bf16 in ws.
__global__ __launch_bounds__(256) void convert(const unsigned int* __restrict__ flag,
                                               const void* __restrict__ src,
                                               u16* __restrict__ dst, int n) {
  int i = (blockIdx.x * 256 + threadIdx.x) * 8;
  if (i >= n) return;
  bf16x8 v;
  if (*flag) {
    const float* s = (const float*)src;
#pragma unroll
    for (int j = 0; j < 8; j++) v[j] = (short)f2bf(s[i + j]);
  } else {
    v = *(const bf16x8*)((const u16*)src + i);
  }
  *(bf16x8*)(dst + i) = v;
}

// ---------------- GEMM: C = A(MxK) * W^T, W stored (N,K) row-major.
// m97 structure: 128x128 tile, BK=32, global_load_lds width=16.
__global__ __launch_bounds__(256) void gemm_bt(
    const u16* __restrict__ A,
    const u16* __restrict__ W0, const u16* __restrict__ W1, const u16* __restrict__ W2,
    void* __restrict__ C0, void* __restrict__ C1, void* __restrict__ C2,
    int M, int N, int K, const unsigned int* __restrict__ flag, int outMode)
{
  const u16* W; void* C;
  if (blockIdx.z == 0)      { W = W0; C = C0; }
  else if (blockIdx.z == 1) { W = W1; C = C1; }
  else                      { W = W2; C = C2; }

  __shared__ __align__(16) u16 sA[128*32];
  __shared__ __align__(16) u16 sB[128*32];

  const int tid  = threadIdx.x;
  const int lane = tid & 63;
  const int w    = tid >> 6;
  const int wm = w >> 1, wn = w & 1;
  const int col = lane & 15, quad = lane >> 4;
  const int bm = blockIdx.y, bn = blockIdx.x;

  floatx4 acc[4][4] = {};

  const int c0 = tid, c1 = tid + 256;
  const size_t aOff0 = (size_t)(bm*128 + (c0 >> 2))*K + (c0 & 3)*8;
  const size_t aOff1 = (size_t)(bm*128 + (c1 >> 2))*K + (c1 & 3)*8;
  const size_t bOff0 = (size_t)(bn*128 + (c0 >> 2))*K + (c0 & 3)*8;
  const size_t bOff1 = (size_t)(bn*128 + (c1 >> 2))*K + (c1 & 3)*8;

  for (int kk = 0; kk < K; kk += 32) {
    gld16(&sA[c0*8], A + aOff0 + kk);
    gld16(&sA[c1*8], A + aOff1 + kk);
    gld16(&sB[c0*8], W + bOff0 + kk);
    gld16(&sB[c1*8], W + bOff1 + kk);
    __syncthreads();
    bf16x8 af[4], bfr[4];
#pragma unroll
    for (int i = 0; i < 4; i++)
      af[i] = *(const bf16x8*)&sA[(wm*64 + i*16 + col)*32 + quad*8];
#pragma unroll
    for (int j = 0; j < 4; j++)
      bfr[j] = *(const bf16x8*)&sB[(wn*64 + j*16 + col)*32 + quad*8];
#pragma unroll
    for (int i = 0; i < 4; i++)
#pragma unroll
      for (int j = 0; j < 4; j++)
        acc[i][j] = __builtin_amdgcn_mfma_f32_16x16x32_bf16(af[i], bfr[j], acc[i][j], 0, 0, 0);
    __syncthreads();
  }

  const bool f32o = outMode && (*flag != 0u);
#pragma unroll
  for (int i = 0; i < 4; i++)
#pragma unroll
    for (int j = 0; j < 4; j++)
#pragma unroll
      for (int r = 0; r < 4; r++) {
        int grow = bm*128 + wm*64 + i*16 + quad*4 + r;
        int gcol = bn*128 + wn*64 + j*16 + col;
        size_t idx = (size_t)grow*N + gcol;
        float v = acc[i][j][r];
        if (f32o) ((float*)C)[idx] = v;
        else      ((u16*)C)[idx]   = f2bf(v);
      }
}

// ---------------- RMSNorm (per 64-elem head) + RoPE, in place on Q and K.
__global__ __launch_bounds__(256) void rmsrope(u16* __restrict__ Q, u16* __restrict__ Kv) {
  const int lane = threadIdx.x & 63;
  const int g = blockIdx.x * 4 + (threadIdx.x >> 6);   // (b*S+s)*H + h
  u16* p = blockIdx.y ? Kv : Q;
  const size_t off = (size_t)g*64 + lane;
  float x = bf2f(p[off]);
  float ss = x*x;
#pragma unroll
  for (int o = 32; o >= 1; o >>= 1) ss += __shfl_xor(ss, o, 64);
  float rn = rsqrtf(ss*(1.0f/64.0f) + 1e-6f);
  float xn = x*rn;
  const int i = lane & 31;
  float c = 1.0f, sn = 0.0f;
  if (i < 16) {
    float freq = exp2f((-10.0f/15.0f) * (float)i);    // (1/1024)^(i/15)
    float th = (float)((g >> 4) & (Ss - 1)) * freq;   // s = (g/H) % S
    c = cosf(th); sn = sinf(th);
  }
  float part = __shfl_xor(xn, 32, 64);
  float y = (lane < 32) ? (xn*c + part*sn) : (xn*c - part*sn);
  p[off] = f2bf(y);
}

// ---------------- Causal flash attention. Block = 4 waves = 64 Q rows of one (b,h).
// QK^T via MFMA (same structure as verified gemm); PV via VALU (bisect round).
__global__ __launch_bounds__(256) void attn(
    const u16* __restrict__ Q, const u16* __restrict__ Kv,
    const u16* __restrict__ V, u16* __restrict__ O)
{
  __shared__ __align__(16) u16 sK[32*72];
  __shared__ __align__(16) u16 sV[32*72];
  __shared__ float sPf[4][16*33];
  __shared__ float sAl[4][16];
  __shared__ float sLi[4][16];

  const int tid  = threadIdx.x;
  const int lane = tid & 63;
  const int w    = tid >> 6;
  const int col = lane & 15, quad = lane >> 4;
  const int rowL = lane >> 2, dg = lane & 3;     // PV mapping: row, dim-group
  const int qt = 31 - blockIdx.x;                // heavy tiles first
  const int bh = blockIdx.y;
  const int b = bh >> 4, h = bh & 15;
  const int q0 = qt * 64;
  const size_t base = (size_t)b*Ss*Dd + (size_t)h*64;

  bf16x8 qf0, qf1;
  {
    const size_t qoff = base + (size_t)(q0 + w*16 + col)*Dd + quad*8;
    qf0 = *(const bf16x8*)(Q + qoff);
    qf1 = *(const bf16x8*)(Q + qoff + 32);
  }

  float o[16];
#pragma unroll
  for (int m = 0; m < 16; m++) o[m] = 0.0f;
  float mi[4], li[4];
#pragma unroll
  for (int r = 0; r < 4; r++) { mi[r] = -1e30f; li[r] = 0.0f; }

  const int nkt  = qt*2 + 2;
  const int wmax = q0 + w*16 + 15;
  const int kr = tid >> 3, kc8 = tid & 7;

  for (int kt = 0; kt < nkt; kt++) {
    const int t0 = kt*32;
    __syncthreads();
    *(bf16x8*)&sK[kr*72 + kc8*8] =
        *(const bf16x8*)(Kv + base + (size_t)(t0 + kr)*Dd + kc8*8);
    *(bf16x8*)&sV[kr*72 + kc8*8] =
        *(const bf16x8*)(V  + base + (size_t)(t0 + kr)*Dd + kc8*8);
    __syncthreads();
    if (t0 <= wmax) {
      floatx4 sc0 = {0.f,0.f,0.f,0.f}, sc1 = {0.f,0.f,0.f,0.f};
      bf16x8 k00 = *(const bf16x8*)&sK[col*72 + quad*8];
      bf16x8 k01 = *(const bf16x8*)&sK[col*72 + 32 + quad*8];
      bf16x8 k10 = *(const bf16x8*)&sK[(16+col)*72 + quad*8];
      bf16x8 k11 = *(const bf16x8*)&sK[(16+col)*72 + 32 + quad*8];
      sc0 = __builtin_amdgcn_mfma_f32_16x16x32_bf16(qf0, k00, sc0, 0,0,0);
      sc0 = __builtin_amdgcn_mfma_f32_16x16x32_bf16(qf1, k01, sc0, 0,0,0);
      sc1 = __builtin_amdgcn_mfma_f32_16x16x32_bf16(qf0, k10, sc1, 0,0,0);
      sc1 = __builtin_amdgcn_mfma_f32_16x16x32_bf16(qf1, k11, sc1, 0,0,0);
#pragma unroll
      for (int r = 0; r < 4; r++) {
        const int qr = q0 + w*16 + quad*4 + r;
        float s0 = sc0[r]*0.125f;              // 1/sqrt(64)
        float s1 = sc1[r]*0.125f;
        if (t0 + col > qr)      s0 = -1e30f;   // finite mask: no infs anywhere
        if (t0 + 16 + col > qr) s1 = -1e30f;
        float mx = fmaxf(s0, s1);
        mx = fmaxf(mx, __shfl_xor(mx, 1, 64));
        mx = fmaxf(mx, __shfl_xor(mx, 2, 64));
        mx = fmaxf(mx, __shfl_xor(mx, 4, 64));
        mx = fmaxf(mx, __shfl_xor(mx, 8, 64));
        float mn = fmaxf(mi[r], mx);
        float al = exp2f((mi[r] - mn)*1.44269504f);
        float p0 = exp2f((s0 - mn)*1.44269504f);
        float p1 = exp2f((s1 - mn)*1.44269504f);
        float ps = p0 + p1;
        ps += __shfl_xor(ps, 1, 64);
        ps += __shfl_xor(ps, 2, 64);
        ps += __shfl_xor(ps, 4, 64);
        ps += __shfl_xor(ps, 8, 64);
        li[r] = li[r]*al + ps;
        mi[r] = mn;
        sPf[w][(quad*4 + r)*33 + col]      = p0;
        sPf[w][(quad*4 + r)*33 + 16 + col] = p1;
        if (col == 0) sAl[w][quad*4 + r] = al;
      }
      // VALU PV: lane handles Q-row rowL, output dims dg*16 .. dg*16+15.
      // Same-wave LDS write->read: DS pipe is in-order per wave.
      float alx = sAl[w][rowL];
#pragma unroll
      for (int m = 0; m < 16; m++) o[m] *= alx;
      for (int t = 0; t < 32; t++) {
        float p = sPf[w][rowL*33 + t];
        bf16x8 v0 = *(const bf16x8*)&sV[t*72 + dg*16];
        bf16x8 v1 = *(const bf16x8*)&sV[t*72 + dg*16 + 8];
#pragma unroll
        for (int j = 0; j < 8; j++) {
          o[j]     += p * bf2f((u16)(unsigned short)v0[j]);
          o[8 + j] += p * bf2f((u16)(unsigned short)v1[j]);
        }
      }
    }
  }
  if (col == 0) {
#pragma unroll
    for (int r = 0; r < 4; r++) sLi[w][quad*4 + r] = li[r];
  }
  float lir = sLi[w][rowL];
  const int orow = q0 + w*16 + rowL;
#pragma unroll
  for (int m = 0; m < 16; m++)
    O[base + (size_t)orow*Dd + dg*16 + m] = f2bf(o[m] / lir);
}

extern "C" void kernel_launch(void* const* d_in, const int* in_sizes, int n_in,
                              void* d_out, int out_size, void* d_ws, size_t ws_size,
                              hipStream_t stream) {
  const void* x  = d_in[0];
  const void* wq = d_in[1];
  const void* wk = d_in[2];
  const void* wv = d_in[3];
  const void* wo = d_in[4];
  // d_in[5] = mask: causal tril, hardcoded in attn kernel.

  const size_t T  = (size_t)Bb*Ss*Dd;   // 4,194,304
  const size_t WN = (size_t)Dd*Dd;      // 1,048,576

  char* ws = (char*)d_ws;
  unsigned int* flag = (unsigned int*)ws;
  u16* xb  = (u16*)(ws + 256);
  u16* wqb = xb  + T;
  u16* wkb = wqb + WN;
  u16* wvb = wkb + WN;
  u16* wob = wvb + WN;
  u16* Qb  = wob + WN;
  u16* Kb  = Qb + T;
  u16* Vb  = Kb + T;
  u16* AO  = Vb + T;                    // total ws use ~48.25 MB

  sniff<<<1, 1024, 0, stream>>>((const unsigned int*)x, flag, 65536);
  convert<<<dim3((int)(T/2048)),  256, 0, stream>>>(flag, x,  xb,  (int)T);
  convert<<<dim3((int)(WN/2048)), 256, 0, stream>>>(flag, wq, wqb, (int)WN);
  convert<<<dim3((int)(WN/2048)), 256, 0, stream>>>(flag, wk, wkb, (int)WN);
  convert<<<dim3((int)(WN/2048)), 256, 0, stream>>>(flag, wv, wvb, (int)WN);
  convert<<<dim3((int)(WN/2048)), 256, 0, stream>>>(flag, wo, wob, (int)WN);

  gemm_bt<<<dim3(8, 32, 3), 256, 0, stream>>>(xb, wqb, wkb, wvb, Qb, Kb, Vb,
                                              4096, 1024, 1024, flag, 0);
  rmsrope<<<dim3((Bb*Ss*Hh)/4, 2), 256, 0, stream>>>(Qb, Kb);
  attn<<<dim3(32, Bb*Hh), 256, 0, stream>>>(Qb, Kb, Vb, AO);
  gemm_bt<<<dim3(8, 32, 1), 256, 0, stream>>>(AO, wob, wob, wob, d_out, d_out, d_out,
                                              4096, 1024, 1024, flag, 1);
}